// Round 4
// baseline (308.613 us; speedup 1.0000x reference)
//
#include <hip/hip_runtime.h>

#define NODES 100000
#define KNN 6

typedef unsigned short u16t;
typedef __attribute__((ext_vector_type(8))) short bf16x8;
typedef __attribute__((ext_vector_type(4))) float f32x4;
union U16 { uint4 u; bf16x8 b; };

__device__ inline f32x4 mfma16(bf16x8 a, bf16x8 b, f32x4 c) {
    return __builtin_amdgcn_mfma_f32_16x16x32_bf16(a, b, c, 0, 0, 0);
}
// pack top-16 bits of two fp32 words (u0 -> low half, u1 -> high half)
__device__ inline unsigned top2(unsigned u1, unsigned u0) {
    return __builtin_amdgcn_perm(u1, u0, 0x07060302u);
}
__device__ inline u16t bf16_rn(float x) {
    unsigned u = __float_as_uint(x);
    return (u16t)((u + 0x7FFF + ((u >> 16) & 1)) >> 16);
}
__device__ inline float bf16_f(u16t h) {
    return __uint_as_float(((unsigned)h) << 16);
}
// truncation split into hi/lo bf16 planes
__device__ inline void split_store(u16t* hp, u16t* lp, float v) {
    const unsigned u = __float_as_uint(v);
    *hp = (u16t)(u >> 16);
    const float hif = __uint_as_float(u & 0xFFFF0000u);
    *lp = (u16t)(__float_as_uint(v - hif) >> 16);
}

// ---------------------------------------------------------------------------
// Weight prep: W[CIN_][N_] fp32 -> MFMA A-operand fragments (hi/lo bf16).
// Fragment (tile t, k-tile kt): elem[n = t*16 + (lane&15)][k = kt*32 + (lane>>4)*8 + j]
template <int CIN_, int N_>
__device__ void prep_dev(const float* __restrict__ W,
                         uint4* __restrict__ fh, uint4* __restrict__ fl, int idx) {
    constexpr int KT = (CIN_ + 31) / 32;
    constexpr int NTt = N_ / 16;
    if (idx >= NTt * KT * 64) return;
    const int lane = idx & 63;
    const int fk = idx >> 6;
    const int kt = fk % KT, t = fk / KT;
    const int n = t * 16 + (lane & 15);
    const int kbase = kt * 32 + (lane >> 4) * 8;
    unsigned h[4], l[4];
    for (int p = 0; p < 4; p++) {
        u16t hh[2], ll[2];
        for (int q = 0; q < 2; q++) {
            const int c = kbase + 2 * p + q;
            const float w = (c < CIN_) ? W[(size_t)c * N_ + n] : 0.f;
            const u16t hi = bf16_rn(w);
            hh[q] = hi;
            ll[q] = bf16_rn(w - bf16_f(hi));
        }
        h[p] = (unsigned)hh[0] | ((unsigned)hh[1] << 16);
        l[p] = (unsigned)ll[0] | ((unsigned)ll[1] << 16);
    }
    fh[idx] = make_uint4(h[0], h[1], h[2], h[3]);
    fl[idx] = make_uint4(l[0], l[1], l[2], l[3]);
}

// W2a: x-rows only (L2 uses the fp32 Δpos VALU path).
// W3a: full 67 rows (L3 keeps pos in the K dimension).
__global__ void prep_all(const float* W1a, const float* W1b,
                         const float* W2a, const float* W2b,
                         const float* W3a, const float* W3b, uint4* wf) {
    const int b = blockIdx.x, t = threadIdx.x;
    if (b == 0)      prep_dev<6, 32>(W1a, wf + 0, wf + 128, t);
    else if (b == 1) prep_dev<32, 32>(W1b, wf + 256, wf + 384, t);
    else if (b == 2) prep_dev<32, 64>(W2a, wf + 512, wf + 768, t);
    else if (b < 5)  prep_dev<64, 64>(W2b, wf + 1024, wf + 1536, (b - 3) * 256 + t);
    else if (b < 11) prep_dev<67, 128>(W3a, wf + 2048, wf + 3584, (b - 5) * 256 + t);
    else             prep_dev<128, 128>(W3b, wf + 5120, wf + 7168, (b - 11) * 256 + t);
}

// ---------------------------------------------------------------------------
// MFMA PointNetConv layer (all 3 layers). Features as separate hi/lo bf16 planes.
// DPOS=false: pos/Δpos channels inside the GEMM1 K dimension (CIN = CX+3, padded).
// DPOS=true : GEMM1 K = x only; Δpos·Wa_p added in exact fp32 VALU (pays when the
//             removed K-tile is a large fraction of GEMM1 — L2 yes, L3 no).
// KSPLIT    : split epilogue+GEMM2 into 2 phases over kt-halves, reusing ONE
//             half-sized Hp buffer. Halves the Hp LDS footprint (L3: 26.6->20.2KB,
//             L2: 28->17.3KB) -> more resident blocks. The kernel is latency-bound
//             (R3: NWAVE=2 halved LDS traffic but cut waves -> regressed), so
//             occupancy is the binding resource. Cost: +2 barriers, acc1 lives
//             through the first GEMM2 half (+~24 VGPR; min-waves 6 caps at ~84).
// GEMM1: A = weights (regs, kt-streamed), B = data (LDS)   rows=channels, cols=edges
// GEMM2: A = data (LDS), B = weights (regs, kt-streamed)   rows=slots,    cols=channels
//
// GEMM2 slot permutation (no padding; E = 48*g tiles of 16):
//   slot s (tile m, w = s&15, quad q = w>>2, reg r = w&3) maps to
//   edge = node*6 + i,  node = (m/3)*8 + 2q + (r>>1),  i = (m%3)*2 + (r&1).
// With this map a node's 6 edges live in ONE lane across the m-triple's
// reg-pairs -> segment max is 6 in-lane fmax, no shuffles, no predication.
template <int CX, int H, int NWAVE, int NB, bool OUTP, bool DPOS, bool KSPLIT>
__global__ __launch_bounds__(NWAVE * 64, 6)
void pnconv_mfma(
    const u16t* __restrict__ xh, const u16t* __restrict__ xl,
    const float* __restrict__ pos, const int* __restrict__ ei,
    const uint4* __restrict__ wfa_hi, const uint4* __restrict__ wfa_lo,
    const float* __restrict__ ba,
    const uint4* __restrict__ wfb_hi, const uint4* __restrict__ wfb_lo,
    const float* __restrict__ bb,
    const float* __restrict__ wpos,   // raw Wa (fp32 [CIN][H]) pos rows; DPOS only
    float* __restrict__ outf, u16t* __restrict__ oh, u16t* __restrict__ ol)
{
    constexpr int NTH = NWAVE * 64;
    constexpr int CIN = DPOS ? CX : CX + 3;  // GEMM1 K channels
    constexpr int K1T = (CIN + 31) / 32;
    constexpr int K2T = H / 32;
    constexpr int NPH = KSPLIT ? 2 : 1;      // epilogue/GEMM2 phases
    constexpr int K2H = K2T / NPH;           // kt per phase
    constexpr int NW = (H / 16) / NWAVE;     // channel tiles per wave
    constexpr int TPP = (H / 16) / NPH;      // channel tiles per phase
    constexpr int E = NB * KNN;
    constexpr int MT1 = E / 16;              // edge tiles (GEMM1 N)
    constexpr int MT2 = E / 16;              // slot tiles (GEMM2 M), unpadded
    constexpr int K1P = K1T * 32 + 8;        // ushort row strides (16B aligned)
    constexpr int K2P = K2H * 32 + 8;        // per-phase Hp row stride
    constexpr int APL = E * K1P;
    constexpr int HPL = E * K2P;
    constexpr int AREQ = 2 * APL + (DPOS ? E * 8 : 0);   // A planes + dpos overlay
    constexpr int SM = (AREQ > 2 * HPL) ? AREQ : 2 * HPL;
    static_assert(E % 48 == 0 && E <= NTH, "tile shape");
    static_assert(MT2 % 3 == 0, "slot perm needs m-triples");
    static_assert(K2T % NPH == 0, "kt split");

    __shared__ __align__(16) u16t smem[SM];
    __shared__ int srcs[E];
    float* const dpf = (float*)&smem[2 * APL];   // DPOS: fp32 Δpos rows [E][4]

    const int tid = threadIdx.x;
    const int lane = tid & 63, wv = tid >> 6;
    const int l15 = lane & 15, quad = lane >> 4;
    const int node0 = blockIdx.x * NB;
    const long e0 = (long)node0 * KNN;

    if (tid < E) srcs[tid] = ei[e0 + tid];

    // GEMM1 weights: kt=0 preload (ping-pong streamed in the loop)
    U16 wah[2][NW], wal[2][NW];
#pragma unroll
    for (int t = 0; t < NW; t++) {
        const int fi = ((wv * NW + t) * K1T) * 64 + lane;
        wah[0][t].u = wfa_hi[fi];
        wal[0][t].u = wfa_lo[fi];
    }
    // pos-row weights Wa[CX+d][ch..ch+3] for the fp32 Δpos term
    f32x4 wpp[NW][3];
    if constexpr (DPOS) {
#pragma unroll
        for (int t = 0; t < NW; t++)
#pragma unroll
            for (int d = 0; d < 3; d++)
                wpp[t][d] = *(const f32x4*)&wpos[(size_t)(CX + d) * H +
                                                (wv * NW + t) * 16 + quad * 4];
    }
    __syncthreads();

    // ---- stage feature planes into LDS (chunk-rotated: bank-conflict-free)
    if constexpr (CX % 8 == 0) {
        constexpr int C8 = CX / 8;
        for (int i = tid; i < E * C8; i += NTH) {
            const int e = i / C8, c0 = i % C8;
            const int c = (c0 + e) & (C8 - 1);   // rotate lane->chunk within the row
            const size_t sb = (size_t)srcs[e] * CX + c * 8;
            *(uint4*)&smem[e * K1P + c * 8] = *(const uint4*)&xh[sb];
            *(uint4*)&smem[APL + e * K1P + c * 8] = *(const uint4*)&xl[sb];
        }
    }
    for (int i = tid; i < E * 3; i += NTH) {
        const int e = i / 3, d = i - 3 * (i / 3);
        const int s = srcs[e], nd = node0 + e / KNN;
        const float sp = pos[3 * s + d];
        const float dl = sp - pos[3 * nd + d];
        if constexpr (DPOS) {
            dpf[e * 4 + d] = dl;                 // exact fp32, used post-GEMM1
        } else {
            if constexpr (CX == 3)
                split_store(&smem[e * K1P + d], &smem[APL + e * K1P + d], sp);
            split_store(&smem[e * K1P + CX + d], &smem[APL + e * K1P + CX + d], dl);
        }
    }
    if constexpr (!DPOS) {
        // zero the K padding (garbage bf16 could be NaN; NaN*0 = NaN)
        constexpr int PADA = (CIN + 7) & ~7;
        constexpr int NU4 = (K1P - PADA) / 8;
        for (int i = tid; i < 2 * E; i += NTH) {
            const int pl = (i >= E) ? 1 : 0;
            const int e = i - pl * E;
            u16t* row = &smem[pl * APL + e * K1P];
            for (int k = CIN; k < PADA; k++) row[k] = 0;
            for (int j = 0; j < NU4; j++) *(uint4*)&row[PADA + j * 8] = make_uint4(0, 0, 0, 0);
        }
    }
    __syncthreads();

    // ---- GEMM1: D[channel][edge] = W1^T * A^T (3-term bf16 split)
    f32x4 acc1[NW][MT1];
#pragma unroll
    for (int t = 0; t < NW; t++)
#pragma unroll
        for (int m = 0; m < MT1; m++) acc1[t][m] = (f32x4){0.f, 0.f, 0.f, 0.f};

#pragma unroll
    for (int kt = 0; kt < K1T; kt++) {
        const int cur = kt & 1, nxt = cur ^ 1;
        if (kt + 1 < K1T) {
#pragma unroll
            for (int t = 0; t < NW; t++) {      // prefetch next kt's weights
                const int fi = ((wv * NW + t) * K1T + kt + 1) * 64 + lane;
                wah[nxt][t].u = wfa_hi[fi];
                wal[nxt][t].u = wfa_lo[fi];
            }
        }
#pragma unroll
        for (int m = 0; m < MT1; m++) {
            const u16t* p = &smem[(m * 16 + l15) * K1P + kt * 32 + quad * 8];
            U16 dh, dl;
            dh.u = *(const uint4*)p;
            dl.u = *(const uint4*)(p + APL);
#pragma unroll
            for (int t = 0; t < NW; t++) {
                acc1[t][m] = mfma16(wah[cur][t].b, dh.b, acc1[t][m]);
                acc1[t][m] = mfma16(wah[cur][t].b, dl.b, acc1[t][m]);
                acc1[t][m] = mfma16(wal[cur][t].b, dh.b, acc1[t][m]);
            }
        }
    }

    // GEMM2 weights: kt=0 preload (latency covered by epilogue + barrier)
    U16 wbh[2][NW], wbl[2][NW];
#pragma unroll
    for (int t = 0; t < NW; t++) {
        const int fi = ((wv * NW + t) * K2T) * 64 + lane;
        wbh[0][t].u = wfb_hi[fi];
        wbl[0][t].u = wfb_lo[fi];
    }

    // ---- Δpos·Wa_p term, exact fp32 (DPOS layers only)
    if constexpr (DPOS) {
#pragma unroll
        for (int m = 0; m < MT1; m++) {
            const f32x4 dp = *(const f32x4*)&dpf[(m * 16 + l15) * 4];
#pragma unroll
            for (int t = 0; t < NW; t++)
#pragma unroll
                for (int j = 0; j < 4; j++)
                    acc1[t][m][j] += wpp[t][0][j] * dp[0] + wpp[t][1][j] * dp[1]
                                   + wpp[t][2][j] * dp[2];
        }
    }

    // ---- GEMM2 slot addressing (phase-local row stride K2P)
    int eaddr[MT2];
#pragma unroll
    for (int m = 0; m < MT2; m++) {
        const int nd_s = (m / 3) * 8 + 2 * (l15 >> 2) + ((l15 >> 1) & 1);
        const int i_s = (m % 3) * 2 + (l15 & 1);
        eaddr[m] = (nd_s * KNN + i_s) * K2P + quad * 8;
    }

    f32x4 acc2[NW][MT2];
#pragma unroll
    for (int t = 0; t < NW; t++)
#pragma unroll
        for (int m = 0; m < MT2; m++) acc2[t][m] = (f32x4){0.f, 0.f, 0.f, 0.f};

    // ---- phased epilogue + GEMM2: per phase, write this kt-half's Hp channels
    //      (owning waves only), then accumulate GEMM2 over that kt-half.
#pragma unroll
    for (int ph = 0; ph < NPH; ph++) {
        __syncthreads();   // ph0: A/dpos reads done; ph1: half-0 Hp reads done

        // ---- bias + relu + trunc-split, write Hp planes (this phase's tiles)
#pragma unroll
        for (int t = 0; t < NW; t++) {
            const int ct = wv * NW + t;
            if (KSPLIT && (ct / TPP) != ph) continue;   // wave-uniform branch
            const int khb = ct * 16 + quad * 4;
            const float4 bs = *(const float4*)&ba[khb];
#pragma unroll
            for (int m = 0; m < MT1; m++) {
                const float v0 = fmaxf(acc1[t][m][0] + bs.x, 0.f);
                const float v1 = fmaxf(acc1[t][m][1] + bs.y, 0.f);
                const float v2 = fmaxf(acc1[t][m][2] + bs.z, 0.f);
                const float v3 = fmaxf(acc1[t][m][3] + bs.w, 0.f);
                const unsigned u0 = __float_as_uint(v0), u1 = __float_as_uint(v1);
                const unsigned u2 = __float_as_uint(v2), u3 = __float_as_uint(v3);
                uint2 hw, lw;
                hw.x = top2(u1, u0);
                hw.y = top2(u3, u2);
                const float l0 = v0 - __uint_as_float(u0 & 0xFFFF0000u);
                const float l1 = v1 - __uint_as_float(u1 & 0xFFFF0000u);
                const float l2 = v2 - __uint_as_float(u2 & 0xFFFF0000u);
                const float l3 = v3 - __uint_as_float(u3 & 0xFFFF0000u);
                lw.x = top2(__float_as_uint(l1), __float_as_uint(l0));
                lw.y = top2(__float_as_uint(l3), __float_as_uint(l2));
                u16t* wp = &smem[(m * 16 + l15) * K2P + khb - ph * (TPP * 16)];
                *(uint2*)wp = hw;
                *(uint2*)(wp + HPL) = lw;
            }
        }
        __syncthreads();

        // ---- GEMM2 (swapped): D[slot][channel] += Hp_half * W2[kt-half]
#pragma unroll
        for (int ktl = 0; ktl < K2H; ktl++) {
            const int kt = ph * K2H + ktl;
            const int cur = kt & 1, nxt = cur ^ 1;
            if (kt + 1 < K2T) {
#pragma unroll
                for (int t = 0; t < NW; t++) {
                    const int fi = ((wv * NW + t) * K2T + kt + 1) * 64 + lane;
                    wbh[nxt][t].u = wfb_hi[fi];
                    wbl[nxt][t].u = wfb_lo[fi];
                }
            }
#pragma unroll
            for (int m = 0; m < MT2; m++) {
                const u16t* p = &smem[eaddr[m] + ktl * 32];
                U16 dh, dl;
                dh.u = *(const uint4*)p;
                dl.u = *(const uint4*)(p + HPL);
#pragma unroll
                for (int t = 0; t < NW; t++) {
                    acc2[t][m] = mfma16(dh.b, wbh[cur][t].b, acc2[t][m]);
                    acc2[t][m] = mfma16(dh.b, wbl[cur][t].b, acc2[t][m]);
                    acc2[t][m] = mfma16(dl.b, wbh[cur][t].b, acc2[t][m]);
                }
            }
        }
    }

    // ---- segment max: fully in-lane (slot perm), 2 nodes per lane per m-triple
#pragma unroll
    for (int t = 0; t < NW; t++) {
        const int nb = (wv * NW + t) * 16;
        const float bias = bb[nb + l15];
#pragma unroll
        for (int g = 0; g < MT2 / 3; g++) {
#pragma unroll
            for (int rp = 0; rp < 2; rp++) {
                float v = fmaxf(
                    fmaxf(fmaxf(acc2[t][3 * g + 0][2 * rp], acc2[t][3 * g + 0][2 * rp + 1]),
                          fmaxf(acc2[t][3 * g + 1][2 * rp], acc2[t][3 * g + 1][2 * rp + 1])),
                    fmaxf(acc2[t][3 * g + 2][2 * rp], acc2[t][3 * g + 2][2 * rp + 1]));
                v = fmaxf(v + bias, 0.f);
                const int node = node0 + g * 8 + 2 * quad + rp;
                const size_t oidx = (size_t)node * H + nb + l15;
                if constexpr (OUTP) {
                    split_store(&oh[oidx], &ol[oidx], v);
                } else {
                    outf[oidx] = v;
                }
            }
        }
    }
}

// ---------------------------------------------------------------------------
extern "C" void kernel_launch(void* const* d_in, const int* in_sizes, int n_in,
                              void* d_out, int out_size, void* d_ws, size_t ws_size,
                              hipStream_t stream) {
    const float* pos = (const float*)d_in[0];
    const int* ei = (const int*)d_in[1];
    const float* W1a = (const float*)d_in[2];
    const float* b1a = (const float*)d_in[3];
    const float* W1b = (const float*)d_in[4];
    const float* b1b = (const float*)d_in[5];
    const float* W2a = (const float*)d_in[6];
    const float* b2a = (const float*)d_in[7];
    const float* W2b = (const float*)d_in[8];
    const float* b2b = (const float*)d_in[9];
    const float* W3a = (const float*)d_in[10];
    const float* b3a = (const float*)d_in[11];
    const float* W3b = (const float*)d_in[12];
    const float* b3b = (const float*)d_in[13];

    u16t* h1h = (u16t*)d_ws;                       // [NODES][32] hi plane
    u16t* h1l = h1h + (size_t)NODES * 32;          // [NODES][32] lo plane
    u16t* h2h = h1l + (size_t)NODES * 32;          // [NODES][64] hi plane
    u16t* h2l = h2h + (size_t)NODES * 64;          // [NODES][64] lo plane
    uint4* wf = (uint4*)(h2l + (size_t)NODES * 64);
    // fragment uint4 offsets:
    //   W1a h/l @0/128, W1b @256/384, W2a (x-rows) @512/768, W2b @1024/1536,
    //   W3a (full 67 rows) @2048/3584, W3b @5120/7168; end 9216

    prep_all<<<19, 256, 0, stream>>>(W1a, W1b, W2a, W2b, W3a, W3b, wf);

    // Layer 1: CX=3 (pos-only), H=32, 2 waves, NB=16, pos in K, no kt-split (K2T=1)
    pnconv_mfma<3, 32, 2, 16, true, false, false><<<NODES / 16, 128, 0, stream>>>(
        nullptr, nullptr, pos, ei,
        wf + 0, wf + 128, b1a, wf + 256, wf + 384, b1b,
        nullptr, nullptr, h1h, h1l);

    // Layer 2: CX=32, H=64, 4 waves (NW=1), NB=16 — fp32 Δpos (K1T=1) + kt-split
    pnconv_mfma<32, 64, 4, 16, true, true, true><<<NODES / 16, 256, 0, stream>>>(
        h1h, h1l, pos, ei,
        wf + 512, wf + 768, b2a, wf + 1024, wf + 1536, b2b,
        W2a, nullptr, h2h, h2l);

    // Layer 3: CX=64, H=128, 4 waves (NW=2), NB=8, fp32 out — pos in K + kt-split
    pnconv_mfma<64, 128, 4, 8, false, false, true><<<NODES / 8, 256, 0, stream>>>(
        h2h, h2l, pos, ei,
        wf + 2048, wf + 3584, b3a, wf + 5120, wf + 7168, b3b,
        nullptr, (float*)d_out, nullptr, nullptr);
}

// Round 5
// 231.900 us; speedup vs baseline: 1.3308x; 1.3308x over previous
//
#include <hip/hip_runtime.h>

#define NODES 100000
#define KNN 6

typedef unsigned short u16t;
typedef __attribute__((ext_vector_type(8))) short bf16x8;
typedef __attribute__((ext_vector_type(4))) float f32x4;
union U16 { uint4 u; bf16x8 b; };

__device__ inline f32x4 mfma16(bf16x8 a, bf16x8 b, f32x4 c) {
    return __builtin_amdgcn_mfma_f32_16x16x32_bf16(a, b, c, 0, 0, 0);
}
// pack top-16 bits of two fp32 words (u0 -> low half, u1 -> high half)
__device__ inline unsigned top2(unsigned u1, unsigned u0) {
    return __builtin_amdgcn_perm(u1, u0, 0x07060302u);
}
__device__ inline u16t bf16_rn(float x) {
    unsigned u = __float_as_uint(x);
    return (u16t)((u + 0x7FFF + ((u >> 16) & 1)) >> 16);
}
__device__ inline float bf16_f(u16t h) {
    return __uint_as_float(((unsigned)h) << 16);
}
// truncation split into hi/lo bf16 planes
__device__ inline void split_store(u16t* hp, u16t* lp, float v) {
    const unsigned u = __float_as_uint(v);
    *hp = (u16t)(u >> 16);
    const float hif = __uint_as_float(u & 0xFFFF0000u);
    *lp = (u16t)(__float_as_uint(v - hif) >> 16);
}

// ---------------------------------------------------------------------------
// Weight prep: W[CIN_][N_] fp32 -> MFMA A-operand fragments (hi/lo bf16).
// Fragment (tile t, k-tile kt): elem[n = t*16 + (lane&15)][k = kt*32 + (lane>>4)*8 + j]
template <int CIN_, int N_>
__device__ void prep_dev(const float* __restrict__ W,
                         uint4* __restrict__ fh, uint4* __restrict__ fl, int idx) {
    constexpr int KT = (CIN_ + 31) / 32;
    constexpr int NTt = N_ / 16;
    if (idx >= NTt * KT * 64) return;
    const int lane = idx & 63;
    const int fk = idx >> 6;
    const int kt = fk % KT, t = fk / KT;
    const int n = t * 16 + (lane & 15);
    const int kbase = kt * 32 + (lane >> 4) * 8;
    unsigned h[4], l[4];
    for (int p = 0; p < 4; p++) {
        u16t hh[2], ll[2];
        for (int q = 0; q < 2; q++) {
            const int c = kbase + 2 * p + q;
            const float w = (c < CIN_) ? W[(size_t)c * N_ + n] : 0.f;
            const u16t hi = bf16_rn(w);
            hh[q] = hi;
            ll[q] = bf16_rn(w - bf16_f(hi));
        }
        h[p] = (unsigned)hh[0] | ((unsigned)hh[1] << 16);
        l[p] = (unsigned)ll[0] | ((unsigned)ll[1] << 16);
    }
    fh[idx] = make_uint4(h[0], h[1], h[2], h[3]);
    fl[idx] = make_uint4(l[0], l[1], l[2], l[3]);
}

// W2a: x-rows only (L2 uses the fp32 Δpos VALU path).
// W3a: full 67 rows (L3 keeps pos in the K dimension — the VALU path regressed
//      there: removed MFMA fraction too small vs added serial VALU chain).
__global__ void prep_all(const float* W1a, const float* W1b,
                         const float* W2a, const float* W2b,
                         const float* W3a, const float* W3b, uint4* wf) {
    const int b = blockIdx.x, t = threadIdx.x;
    if (b == 0)      prep_dev<6, 32>(W1a, wf + 0, wf + 128, t);
    else if (b == 1) prep_dev<32, 32>(W1b, wf + 256, wf + 384, t);
    else if (b == 2) prep_dev<32, 64>(W2a, wf + 512, wf + 768, t);
    else if (b < 5)  prep_dev<64, 64>(W2b, wf + 1024, wf + 1536, (b - 3) * 256 + t);
    else if (b < 11) prep_dev<67, 128>(W3a, wf + 2048, wf + 3584, (b - 5) * 256 + t);
    else             prep_dev<128, 128>(W3b, wf + 5120, wf + 7168, (b - 11) * 256 + t);
}

// ---------------------------------------------------------------------------
// MFMA PointNetConv layer (all 3 layers). Features as separate hi/lo bf16 planes.
// DPOS=false: pos/Δpos channels inside the GEMM1 K dimension (CIN = CX+3, padded).
// DPOS=true : GEMM1 K = x only (exact K-tiles); the Δpos·Wa_p term is added in
//             exact fp32 VALU from an LDS-staged Δpos[E][4] array. Only pays when
//             the removed K-tile is a large fraction of GEMM1 (L2: 50%; L3: no).
// GEMM1: A = weights (regs, kt-streamed), B = data (LDS)   rows=channels, cols=edges
// GEMM2: A = data (LDS), B = weights (regs, kt-streamed)   rows=slots,    cols=channels
//
// Session ledger (dispatch-level, in-run evidence):
//   L3 pos-in-K ~89-95us beats L3 DPOS 105.8us; L2 DPOS beats L2 pos-in-K ~-21us.
//   NWAVE=2 (R3): halves LDS traffic+conflicts but cuts resident waves -> regressed
//     (latency-bound, occupancy is the binding resource).
//   KSPLIT @ min-waves 6 (R4): LDS 26.6->20.5KB, occupancy 60%, but 85-VGPR cap
//     forced scratch spill (FETCH+WRITE +377MB) -> catastrophic. Don't cap regs
//     below the live set.
// This is the best-evidenced composition: NWAVE=4, min-waves 4, no KSPLIT.
//
// GEMM2 slot permutation (no padding; E = 48*g tiles of 16):
//   slot s (tile m, w = s&15, quad q = w>>2, reg r = w&3) maps to
//   edge = node*6 + i,  node = (m/3)*8 + 2q + (r>>1),  i = (m%3)*2 + (r&1).
// With this map a node's 6 edges live in ONE lane across the m-triple's
// reg-pairs -> segment max is 6 in-lane fmax, no shuffles, no predication.
template <int CX, int H, int NWAVE, int NB, bool OUTP, bool DPOS>
__global__ __launch_bounds__(NWAVE * 64, 4) void pnconv_mfma(
    const u16t* __restrict__ xh, const u16t* __restrict__ xl,
    const float* __restrict__ pos, const int* __restrict__ ei,
    const uint4* __restrict__ wfa_hi, const uint4* __restrict__ wfa_lo,
    const float* __restrict__ ba,
    const uint4* __restrict__ wfb_hi, const uint4* __restrict__ wfb_lo,
    const float* __restrict__ bb,
    const float* __restrict__ wpos,   // raw Wa (fp32 [CIN][H]) pos rows; DPOS only
    float* __restrict__ outf, u16t* __restrict__ oh, u16t* __restrict__ ol)
{
    constexpr int NTH = NWAVE * 64;
    constexpr int CIN = DPOS ? CX : CX + 3;  // GEMM1 K channels
    constexpr int K1T = (CIN + 31) / 32;
    constexpr int K2T = H / 32;
    constexpr int NW = (H / 16) / NWAVE;     // channel tiles per wave
    constexpr int E = NB * KNN;
    constexpr int MT1 = E / 16;              // edge tiles (GEMM1 N)
    constexpr int MT2 = E / 16;              // slot tiles (GEMM2 M), unpadded
    constexpr int K1P = K1T * 32 + 8;        // ushort row strides (16B aligned)
    constexpr int K2P = K2T * 32 + 8;
    constexpr int APL = E * K1P;
    constexpr int HPL = E * K2P;
    constexpr int SM = (2 * APL > 2 * HPL) ? 2 * APL : 2 * HPL;
    static_assert(E % 48 == 0 && E <= NTH, "tile shape");
    static_assert(MT2 % 3 == 0, "slot perm needs m-triples");
    static_assert(!DPOS || (2 * APL + E * 8) <= SM, "dpos overlay fits");

    __shared__ __align__(16) u16t smem[SM];
    __shared__ int srcs[E];
    float* const dpf = (float*)&smem[2 * APL];   // DPOS: fp32 Δpos rows [E][4]

    const int tid = threadIdx.x;
    const int lane = tid & 63, wv = tid >> 6;
    const int l15 = lane & 15, quad = lane >> 4;
    const int node0 = blockIdx.x * NB;
    const long e0 = (long)node0 * KNN;

    if (tid < E) srcs[tid] = ei[e0 + tid];

    // GEMM1 weights: kt=0 preload (ping-pong streamed in the loop)
    U16 wah[2][NW], wal[2][NW];
#pragma unroll
    for (int t = 0; t < NW; t++) {
        const int fi = ((wv * NW + t) * K1T) * 64 + lane;
        wah[0][t].u = wfa_hi[fi];
        wal[0][t].u = wfa_lo[fi];
    }
    // pos-row weights Wa[CX+d][ch..ch+3] for the fp32 Δpos term
    f32x4 wpp[NW][3];
    if constexpr (DPOS) {
#pragma unroll
        for (int t = 0; t < NW; t++)
#pragma unroll
            for (int d = 0; d < 3; d++)
                wpp[t][d] = *(const f32x4*)&wpos[(size_t)(CX + d) * H +
                                                (wv * NW + t) * 16 + quad * 4];
    }
    __syncthreads();

    // ---- stage feature planes into LDS (chunk-rotated: bank-conflict-free)
    if constexpr (CX % 8 == 0) {
        constexpr int C8 = CX / 8;
        for (int i = tid; i < E * C8; i += NTH) {
            const int e = i / C8, c0 = i % C8;
            const int c = (c0 + e) & (C8 - 1);   // rotate lane->chunk within the row
            const size_t sb = (size_t)srcs[e] * CX + c * 8;
            *(uint4*)&smem[e * K1P + c * 8] = *(const uint4*)&xh[sb];
            *(uint4*)&smem[APL + e * K1P + c * 8] = *(const uint4*)&xl[sb];
        }
    }
    for (int i = tid; i < E * 3; i += NTH) {
        const int e = i / 3, d = i - 3 * (i / 3);
        const int s = srcs[e], nd = node0 + e / KNN;
        const float sp = pos[3 * s + d];
        const float dl = sp - pos[3 * nd + d];
        if constexpr (DPOS) {
            dpf[e * 4 + d] = dl;                 // exact fp32, used post-GEMM1
        } else {
            if constexpr (CX == 3)
                split_store(&smem[e * K1P + d], &smem[APL + e * K1P + d], sp);
            split_store(&smem[e * K1P + CX + d], &smem[APL + e * K1P + CX + d], dl);
        }
    }
    if constexpr (!DPOS) {
        // zero the K padding (garbage bf16 could be NaN; NaN*0 = NaN)
        constexpr int PADA = (CIN + 7) & ~7;
        constexpr int NU4 = (K1P - PADA) / 8;
        for (int i = tid; i < 2 * E; i += NTH) {
            const int pl = (i >= E) ? 1 : 0;
            const int e = i - pl * E;
            u16t* row = &smem[pl * APL + e * K1P];
            for (int k = CIN; k < PADA; k++) row[k] = 0;
            for (int j = 0; j < NU4; j++) *(uint4*)&row[PADA + j * 8] = make_uint4(0, 0, 0, 0);
        }
    }
    __syncthreads();

    // ---- GEMM1: D[channel][edge] = W1^T * A^T (3-term bf16 split)
    f32x4 acc1[NW][MT1];
#pragma unroll
    for (int t = 0; t < NW; t++)
#pragma unroll
        for (int m = 0; m < MT1; m++) acc1[t][m] = (f32x4){0.f, 0.f, 0.f, 0.f};

#pragma unroll
    for (int kt = 0; kt < K1T; kt++) {
        const int cur = kt & 1, nxt = cur ^ 1;
        if (kt + 1 < K1T) {
#pragma unroll
            for (int t = 0; t < NW; t++) {      // prefetch next kt's weights
                const int fi = ((wv * NW + t) * K1T + kt + 1) * 64 + lane;
                wah[nxt][t].u = wfa_hi[fi];
                wal[nxt][t].u = wfa_lo[fi];
            }
        }
#pragma unroll
        for (int m = 0; m < MT1; m++) {
            const u16t* p = &smem[(m * 16 + l15) * K1P + kt * 32 + quad * 8];
            U16 dh, dl;
            dh.u = *(const uint4*)p;
            dl.u = *(const uint4*)(p + APL);
#pragma unroll
            for (int t = 0; t < NW; t++) {
                acc1[t][m] = mfma16(wah[cur][t].b, dh.b, acc1[t][m]);
                acc1[t][m] = mfma16(wah[cur][t].b, dl.b, acc1[t][m]);
                acc1[t][m] = mfma16(wal[cur][t].b, dh.b, acc1[t][m]);
            }
        }
    }

    // GEMM2 weights: kt=0 preload (latency covered by epilogue + barrier)
    U16 wbh[2][NW], wbl[2][NW];
#pragma unroll
    for (int t = 0; t < NW; t++) {
        const int fi = ((wv * NW + t) * K2T) * 64 + lane;
        wbh[0][t].u = wfb_hi[fi];
        wbl[0][t].u = wfb_lo[fi];
    }

    // ---- Δpos·Wa_p term, exact fp32 (DPOS layers only)
    if constexpr (DPOS) {
#pragma unroll
        for (int m = 0; m < MT1; m++) {
            const f32x4 dp = *(const f32x4*)&dpf[(m * 16 + l15) * 4];
#pragma unroll
            for (int t = 0; t < NW; t++)
#pragma unroll
                for (int j = 0; j < 4; j++)
                    acc1[t][m][j] += wpp[t][0][j] * dp[0] + wpp[t][1][j] * dp[1]
                                   + wpp[t][2][j] * dp[2];
        }
    }
    __syncthreads();   // all A/dpos reads done; smem becomes Hp planes

    // ---- bias + relu + trunc-split, write Hp planes
#pragma unroll
    for (int t = 0; t < NW; t++) {
        const int khb = (wv * NW + t) * 16 + quad * 4;
        const float4 bs = *(const float4*)&ba[khb];
#pragma unroll
        for (int m = 0; m < MT1; m++) {
            const float v0 = fmaxf(acc1[t][m][0] + bs.x, 0.f);
            const float v1 = fmaxf(acc1[t][m][1] + bs.y, 0.f);
            const float v2 = fmaxf(acc1[t][m][2] + bs.z, 0.f);
            const float v3 = fmaxf(acc1[t][m][3] + bs.w, 0.f);
            const unsigned u0 = __float_as_uint(v0), u1 = __float_as_uint(v1);
            const unsigned u2 = __float_as_uint(v2), u3 = __float_as_uint(v3);
            uint2 hw, lw;
            hw.x = top2(u1, u0);
            hw.y = top2(u3, u2);
            const float l0 = v0 - __uint_as_float(u0 & 0xFFFF0000u);
            const float l1 = v1 - __uint_as_float(u1 & 0xFFFF0000u);
            const float l2 = v2 - __uint_as_float(u2 & 0xFFFF0000u);
            const float l3 = v3 - __uint_as_float(u3 & 0xFFFF0000u);
            lw.x = top2(__float_as_uint(l1), __float_as_uint(l0));
            lw.y = top2(__float_as_uint(l3), __float_as_uint(l2));
            u16t* wp = &smem[(m * 16 + l15) * K2P + khb];
            *(uint2*)wp = hw;
            *(uint2*)(wp + HPL) = lw;
        }
    }
    __syncthreads();

    // ---- GEMM2 (swapped): D[slot][channel] = Hp * W2, weights streamed per kt
    int eaddr[MT2];
#pragma unroll
    for (int m = 0; m < MT2; m++) {
        const int nd_s = (m / 3) * 8 + 2 * (l15 >> 2) + ((l15 >> 1) & 1);
        const int i_s = (m % 3) * 2 + (l15 & 1);
        eaddr[m] = (nd_s * KNN + i_s) * K2P + quad * 8;
    }

    f32x4 acc2[NW][MT2];
#pragma unroll
    for (int t = 0; t < NW; t++)
#pragma unroll
        for (int m = 0; m < MT2; m++) acc2[t][m] = (f32x4){0.f, 0.f, 0.f, 0.f};

#pragma unroll
    for (int kt = 0; kt < K2T; kt++) {
        const int cur = kt & 1, nxt = cur ^ 1;
        if (kt + 1 < K2T) {
#pragma unroll
            for (int t = 0; t < NW; t++) {
                const int fi = ((wv * NW + t) * K2T + kt + 1) * 64 + lane;
                wbh[nxt][t].u = wfb_hi[fi];
                wbl[nxt][t].u = wfb_lo[fi];
            }
        }
#pragma unroll
        for (int m = 0; m < MT2; m++) {
            const u16t* p = &smem[eaddr[m] + kt * 32];
            U16 dh, dl;
            dh.u = *(const uint4*)p;
            dl.u = *(const uint4*)(p + HPL);
#pragma unroll
            for (int t = 0; t < NW; t++) {
                acc2[t][m] = mfma16(dh.b, wbh[cur][t].b, acc2[t][m]);
                acc2[t][m] = mfma16(dh.b, wbl[cur][t].b, acc2[t][m]);
                acc2[t][m] = mfma16(dl.b, wbh[cur][t].b, acc2[t][m]);
            }
        }
    }

    // ---- segment max: fully in-lane (slot perm), 2 nodes per lane per m-triple
#pragma unroll
    for (int t = 0; t < NW; t++) {
        const int nb = (wv * NW + t) * 16;
        const float bias = bb[nb + l15];
#pragma unroll
        for (int g = 0; g < MT2 / 3; g++) {
#pragma unroll
            for (int rp = 0; rp < 2; rp++) {
                float v = fmaxf(
                    fmaxf(fmaxf(acc2[t][3 * g + 0][2 * rp], acc2[t][3 * g + 0][2 * rp + 1]),
                          fmaxf(acc2[t][3 * g + 1][2 * rp], acc2[t][3 * g + 1][2 * rp + 1])),
                    fmaxf(acc2[t][3 * g + 2][2 * rp], acc2[t][3 * g + 2][2 * rp + 1]));
                v = fmaxf(v + bias, 0.f);
                const int node = node0 + g * 8 + 2 * quad + rp;
                const size_t oidx = (size_t)node * H + nb + l15;
                if constexpr (OUTP) {
                    split_store(&oh[oidx], &ol[oidx], v);
                } else {
                    outf[oidx] = v;
                }
            }
        }
    }
}

// ---------------------------------------------------------------------------
extern "C" void kernel_launch(void* const* d_in, const int* in_sizes, int n_in,
                              void* d_out, int out_size, void* d_ws, size_t ws_size,
                              hipStream_t stream) {
    const float* pos = (const float*)d_in[0];
    const int* ei = (const int*)d_in[1];
    const float* W1a = (const float*)d_in[2];
    const float* b1a = (const float*)d_in[3];
    const float* W1b = (const float*)d_in[4];
    const float* b1b = (const float*)d_in[5];
    const float* W2a = (const float*)d_in[6];
    const float* b2a = (const float*)d_in[7];
    const float* W2b = (const float*)d_in[8];
    const float* b2b = (const float*)d_in[9];
    const float* W3a = (const float*)d_in[10];
    const float* b3a = (const float*)d_in[11];
    const float* W3b = (const float*)d_in[12];
    const float* b3b = (const float*)d_in[13];

    u16t* h1h = (u16t*)d_ws;                       // [NODES][32] hi plane
    u16t* h1l = h1h + (size_t)NODES * 32;          // [NODES][32] lo plane
    u16t* h2h = h1l + (size_t)NODES * 32;          // [NODES][64] hi plane
    u16t* h2l = h2h + (size_t)NODES * 64;          // [NODES][64] lo plane
    uint4* wf = (uint4*)(h2l + (size_t)NODES * 64);
    // fragment uint4 offsets:
    //   W1a h/l @0/128, W1b @256/384, W2a (x-rows) @512/768, W2b @1024/1536,
    //   W3a (full 67 rows) @2048/3584, W3b @5120/7168; end 9216

    prep_all<<<19, 256, 0, stream>>>(W1a, W1b, W2a, W2b, W3a, W3b, wf);

    // Layer 1: CX=3 (pos-only), H=32, 2 waves, NB=16, pos in K
    pnconv_mfma<3, 32, 2, 16, true, false><<<NODES / 16, 128, 0, stream>>>(
        nullptr, nullptr, pos, ei,
        wf + 0, wf + 128, b1a, wf + 256, wf + 384, b1b,
        nullptr, nullptr, h1h, h1l);

    // Layer 2: CX=32, H=64, 4 waves (NW=1), NB=16 — fp32 Δpos path (K1T=1)
    pnconv_mfma<32, 64, 4, 16, true, true><<<NODES / 16, 256, 0, stream>>>(
        h1h, h1l, pos, ei,
        wf + 512, wf + 768, b2a, wf + 1024, wf + 1536, b2b,
        W2a, nullptr, h2h, h2l);

    // Layer 3: CX=64, H=128, 4 waves (NW=2), NB=8, fp32 output — pos in K (K1T=3)
    pnconv_mfma<64, 128, 4, 8, false, false><<<NODES / 8, 256, 0, stream>>>(
        h2h, h2l, pos, ei,
        wf + 2048, wf + 3584, b3a, wf + 5120, wf + 7168, b3b,
        nullptr, (float*)d_out, nullptr, nullptr);
}

// Round 6
// 225.144 us; speedup vs baseline: 1.3707x; 1.0300x over previous
//
#include <hip/hip_runtime.h>

#define NODES 100000
#define KNN 6

typedef unsigned short u16t;
typedef __attribute__((ext_vector_type(8))) short bf16x8;
typedef __attribute__((ext_vector_type(4))) float f32x4;
union U16 { uint4 u; bf16x8 b; };

__device__ inline f32x4 mfma16(bf16x8 a, bf16x8 b, f32x4 c) {
    return __builtin_amdgcn_mfma_f32_16x16x32_bf16(a, b, c, 0, 0, 0);
}
// pack top-16 bits of two fp32 words (u0 -> low half, u1 -> high half)
__device__ inline unsigned top2(unsigned u1, unsigned u0) {
    return __builtin_amdgcn_perm(u1, u0, 0x07060302u);
}
__device__ inline u16t bf16_rn(float x) {
    unsigned u = __float_as_uint(x);
    return (u16t)((u + 0x7FFF + ((u >> 16) & 1)) >> 16);
}
__device__ inline float bf16_f(u16t h) {
    return __uint_as_float(((unsigned)h) << 16);
}
// truncation split into hi/lo bf16 planes
__device__ inline void split_store(u16t* hp, u16t* lp, float v) {
    const unsigned u = __float_as_uint(v);
    *hp = (u16t)(u >> 16);
    const float hif = __uint_as_float(u & 0xFFFF0000u);
    *lp = (u16t)(__float_as_uint(v - hif) >> 16);
}

// ---------------------------------------------------------------------------
// Weight prep: W[CIN_][N_] fp32 -> MFMA A-operand fragments (hi/lo bf16).
// Fragment (tile t, k-tile kt): elem[n = t*16 + (lane&15)][k = kt*32 + (lane>>4)*8 + j]
template <int CIN_, int N_>
__device__ void prep_dev(const float* __restrict__ W,
                         uint4* __restrict__ fh, uint4* __restrict__ fl, int idx) {
    constexpr int KT = (CIN_ + 31) / 32;
    constexpr int NTt = N_ / 16;
    if (idx >= NTt * KT * 64) return;
    const int lane = idx & 63;
    const int fk = idx >> 6;
    const int kt = fk % KT, t = fk / KT;
    const int n = t * 16 + (lane & 15);
    const int kbase = kt * 32 + (lane >> 4) * 8;
    unsigned h[4], l[4];
    for (int p = 0; p < 4; p++) {
        u16t hh[2], ll[2];
        for (int q = 0; q < 2; q++) {
            const int c = kbase + 2 * p + q;
            const float w = (c < CIN_) ? W[(size_t)c * N_ + n] : 0.f;
            const u16t hi = bf16_rn(w);
            hh[q] = hi;
            ll[q] = bf16_rn(w - bf16_f(hi));
        }
        h[p] = (unsigned)hh[0] | ((unsigned)hh[1] << 16);
        l[p] = (unsigned)ll[0] | ((unsigned)ll[1] << 16);
    }
    fh[idx] = make_uint4(h[0], h[1], h[2], h[3]);
    fl[idx] = make_uint4(l[0], l[1], l[2], l[3]);
}

// W2a: x-rows only (L2 uses the fp32 Δpos VALU path).
// W3a: full 67 rows (L3 keeps pos in the K dimension — the VALU path regressed
//      there: removed MFMA fraction too small vs added serial VALU chain).
__global__ void prep_all(const float* W1a, const float* W1b,
                         const float* W2a, const float* W2b,
                         const float* W3a, const float* W3b, uint4* wf) {
    const int b = blockIdx.x, t = threadIdx.x;
    if (b == 0)      prep_dev<6, 32>(W1a, wf + 0, wf + 128, t);
    else if (b == 1) prep_dev<32, 32>(W1b, wf + 256, wf + 384, t);
    else if (b == 2) prep_dev<32, 64>(W2a, wf + 512, wf + 768, t);
    else if (b < 5)  prep_dev<64, 64>(W2b, wf + 1024, wf + 1536, (b - 3) * 256 + t);
    else if (b < 11) prep_dev<67, 128>(W3a, wf + 2048, wf + 3584, (b - 5) * 256 + t);
    else             prep_dev<128, 128>(W3b, wf + 5120, wf + 7168, (b - 11) * 256 + t);
}

// ---------------------------------------------------------------------------
// MFMA PointNetConv layer (all 3 layers). Features as separate hi/lo bf16 planes.
// DPOS=false: pos/Δpos channels inside the GEMM1 K dimension (CIN = CX+3, padded).
// DPOS=true : GEMM1 K = x only (exact K-tiles); the Δpos·Wa_p term is added in
//             exact fp32 VALU from an LDS-staged Δpos[E][4] array. Only pays when
//             the removed K-tile is a large fraction of GEMM1 (L2: 50%; L3: no).
// GEMM1: A = weights (regs, kt-streamed), B = data (LDS)   rows=channels, cols=edges
// GEMM2: A = data (LDS), B = weights (regs, kt-streamed)   rows=slots,    cols=channels
//
// Session ledger (dispatch-level, in-run evidence):
//   L3 pos-in-K ~89-95us beats L3 DPOS 105.8us; L2 DPOS beats L2 pos-in-K ~-21us.
//   NWAVE=2 (R3): halves LDS traffic+conflicts but cuts resident waves -> regressed
//     (latency-bound, occupancy is the binding resource).
//   KSPLIT @ min-waves 6 (R4): LDS down, occupancy 60%, but 85-VGPR cap forced
//     scratch spill (FETCH+WRITE +377MB) -> catastrophic. Don't cap regs below
//     the live set.
//   R6: L1/L2 are gather-latency-bound (random kNN indices; MFMA floor ~10% of
//     their dur) and LDS-capped at 20 waves/CU (62%). NB 16->8 halves their LDS
//     (L2 27.6->14KB, L1 15.4->8KB) -> wave-cap 32/CU (100%). L3 untouched.
//
// GEMM2 slot permutation (no padding; E = 48*g tiles of 16):
//   slot s (tile m, w = s&15, quad q = w>>2, reg r = w&3) maps to
//   edge = node*6 + i,  node = (m/3)*8 + 2q + (r>>1),  i = (m%3)*2 + (r&1).
// With this map a node's 6 edges live in ONE lane across the m-triple's
// reg-pairs -> segment max is 6 in-lane fmax, no shuffles, no predication.
template <int CX, int H, int NWAVE, int NB, bool OUTP, bool DPOS>
__global__ __launch_bounds__(NWAVE * 64, 4) void pnconv_mfma(
    const u16t* __restrict__ xh, const u16t* __restrict__ xl,
    const float* __restrict__ pos, const int* __restrict__ ei,
    const uint4* __restrict__ wfa_hi, const uint4* __restrict__ wfa_lo,
    const float* __restrict__ ba,
    const uint4* __restrict__ wfb_hi, const uint4* __restrict__ wfb_lo,
    const float* __restrict__ bb,
    const float* __restrict__ wpos,   // raw Wa (fp32 [CIN][H]) pos rows; DPOS only
    float* __restrict__ outf, u16t* __restrict__ oh, u16t* __restrict__ ol)
{
    constexpr int NTH = NWAVE * 64;
    constexpr int CIN = DPOS ? CX : CX + 3;  // GEMM1 K channels
    constexpr int K1T = (CIN + 31) / 32;
    constexpr int K2T = H / 32;
    constexpr int NW = (H / 16) / NWAVE;     // channel tiles per wave
    constexpr int E = NB * KNN;
    constexpr int MT1 = E / 16;              // edge tiles (GEMM1 N)
    constexpr int MT2 = E / 16;              // slot tiles (GEMM2 M), unpadded
    constexpr int K1P = K1T * 32 + 8;        // ushort row strides (16B aligned)
    constexpr int K2P = K2T * 32 + 8;
    constexpr int APL = E * K1P;
    constexpr int HPL = E * K2P;
    constexpr int SM = (2 * APL > 2 * HPL) ? 2 * APL : 2 * HPL;
    static_assert(E % 48 == 0 && E <= NTH, "tile shape");
    static_assert(MT2 % 3 == 0, "slot perm needs m-triples");
    static_assert(!DPOS || (2 * APL + E * 8) <= SM, "dpos overlay fits");

    __shared__ __align__(16) u16t smem[SM];
    __shared__ int srcs[E];
    float* const dpf = (float*)&smem[2 * APL];   // DPOS: fp32 Δpos rows [E][4]

    const int tid = threadIdx.x;
    const int lane = tid & 63, wv = tid >> 6;
    const int l15 = lane & 15, quad = lane >> 4;
    const int node0 = blockIdx.x * NB;
    const long e0 = (long)node0 * KNN;

    if (tid < E) srcs[tid] = ei[e0 + tid];

    // GEMM1 weights: kt=0 preload (ping-pong streamed in the loop)
    U16 wah[2][NW], wal[2][NW];
#pragma unroll
    for (int t = 0; t < NW; t++) {
        const int fi = ((wv * NW + t) * K1T) * 64 + lane;
        wah[0][t].u = wfa_hi[fi];
        wal[0][t].u = wfa_lo[fi];
    }
    // pos-row weights Wa[CX+d][ch..ch+3] for the fp32 Δpos term
    f32x4 wpp[NW][3];
    if constexpr (DPOS) {
#pragma unroll
        for (int t = 0; t < NW; t++)
#pragma unroll
            for (int d = 0; d < 3; d++)
                wpp[t][d] = *(const f32x4*)&wpos[(size_t)(CX + d) * H +
                                                (wv * NW + t) * 16 + quad * 4];
    }
    __syncthreads();

    // ---- stage feature planes into LDS (chunk-rotated: bank-conflict-free)
    if constexpr (CX % 8 == 0) {
        constexpr int C8 = CX / 8;
        for (int i = tid; i < E * C8; i += NTH) {
            const int e = i / C8, c0 = i % C8;
            const int c = (c0 + e) & (C8 - 1);   // rotate lane->chunk within the row
            const size_t sb = (size_t)srcs[e] * CX + c * 8;
            *(uint4*)&smem[e * K1P + c * 8] = *(const uint4*)&xh[sb];
            *(uint4*)&smem[APL + e * K1P + c * 8] = *(const uint4*)&xl[sb];
        }
    }
    for (int i = tid; i < E * 3; i += NTH) {
        const int e = i / 3, d = i - 3 * (i / 3);
        const int s = srcs[e], nd = node0 + e / KNN;
        const float sp = pos[3 * s + d];
        const float dl = sp - pos[3 * nd + d];
        if constexpr (DPOS) {
            dpf[e * 4 + d] = dl;                 // exact fp32, used post-GEMM1
        } else {
            if constexpr (CX == 3)
                split_store(&smem[e * K1P + d], &smem[APL + e * K1P + d], sp);
            split_store(&smem[e * K1P + CX + d], &smem[APL + e * K1P + CX + d], dl);
        }
    }
    if constexpr (!DPOS) {
        // zero the K padding (garbage bf16 could be NaN; NaN*0 = NaN)
        constexpr int PADA = (CIN + 7) & ~7;
        constexpr int NU4 = (K1P - PADA) / 8;
        for (int i = tid; i < 2 * E; i += NTH) {
            const int pl = (i >= E) ? 1 : 0;
            const int e = i - pl * E;
            u16t* row = &smem[pl * APL + e * K1P];
            for (int k = CIN; k < PADA; k++) row[k] = 0;
            for (int j = 0; j < NU4; j++) *(uint4*)&row[PADA + j * 8] = make_uint4(0, 0, 0, 0);
        }
    }
    __syncthreads();

    // ---- GEMM1: D[channel][edge] = W1^T * A^T (3-term bf16 split)
    f32x4 acc1[NW][MT1];
#pragma unroll
    for (int t = 0; t < NW; t++)
#pragma unroll
        for (int m = 0; m < MT1; m++) acc1[t][m] = (f32x4){0.f, 0.f, 0.f, 0.f};

#pragma unroll
    for (int kt = 0; kt < K1T; kt++) {
        const int cur = kt & 1, nxt = cur ^ 1;
        if (kt + 1 < K1T) {
#pragma unroll
            for (int t = 0; t < NW; t++) {      // prefetch next kt's weights
                const int fi = ((wv * NW + t) * K1T + kt + 1) * 64 + lane;
                wah[nxt][t].u = wfa_hi[fi];
                wal[nxt][t].u = wfa_lo[fi];
            }
        }
#pragma unroll
        for (int m = 0; m < MT1; m++) {
            const u16t* p = &smem[(m * 16 + l15) * K1P + kt * 32 + quad * 8];
            U16 dh, dl;
            dh.u = *(const uint4*)p;
            dl.u = *(const uint4*)(p + APL);
#pragma unroll
            for (int t = 0; t < NW; t++) {
                acc1[t][m] = mfma16(wah[cur][t].b, dh.b, acc1[t][m]);
                acc1[t][m] = mfma16(wah[cur][t].b, dl.b, acc1[t][m]);
                acc1[t][m] = mfma16(wal[cur][t].b, dh.b, acc1[t][m]);
            }
        }
    }

    // GEMM2 weights: kt=0 preload (latency covered by epilogue + barrier)
    U16 wbh[2][NW], wbl[2][NW];
#pragma unroll
    for (int t = 0; t < NW; t++) {
        const int fi = ((wv * NW + t) * K2T) * 64 + lane;
        wbh[0][t].u = wfb_hi[fi];
        wbl[0][t].u = wfb_lo[fi];
    }

    // ---- Δpos·Wa_p term, exact fp32 (DPOS layers only)
    if constexpr (DPOS) {
#pragma unroll
        for (int m = 0; m < MT1; m++) {
            const f32x4 dp = *(const f32x4*)&dpf[(m * 16 + l15) * 4];
#pragma unroll
            for (int t = 0; t < NW; t++)
#pragma unroll
                for (int j = 0; j < 4; j++)
                    acc1[t][m][j] += wpp[t][0][j] * dp[0] + wpp[t][1][j] * dp[1]
                                   + wpp[t][2][j] * dp[2];
        }
    }
    __syncthreads();   // all A/dpos reads done; smem becomes Hp planes

    // ---- bias + relu + trunc-split, write Hp planes
#pragma unroll
    for (int t = 0; t < NW; t++) {
        const int khb = (wv * NW + t) * 16 + quad * 4;
        const float4 bs = *(const float4*)&ba[khb];
#pragma unroll
        for (int m = 0; m < MT1; m++) {
            const float v0 = fmaxf(acc1[t][m][0] + bs.x, 0.f);
            const float v1 = fmaxf(acc1[t][m][1] + bs.y, 0.f);
            const float v2 = fmaxf(acc1[t][m][2] + bs.z, 0.f);
            const float v3 = fmaxf(acc1[t][m][3] + bs.w, 0.f);
            const unsigned u0 = __float_as_uint(v0), u1 = __float_as_uint(v1);
            const unsigned u2 = __float_as_uint(v2), u3 = __float_as_uint(v3);
            uint2 hw, lw;
            hw.x = top2(u1, u0);
            hw.y = top2(u3, u2);
            const float l0 = v0 - __uint_as_float(u0 & 0xFFFF0000u);
            const float l1 = v1 - __uint_as_float(u1 & 0xFFFF0000u);
            const float l2 = v2 - __uint_as_float(u2 & 0xFFFF0000u);
            const float l3 = v3 - __uint_as_float(u3 & 0xFFFF0000u);
            lw.x = top2(__float_as_uint(l1), __float_as_uint(l0));
            lw.y = top2(__float_as_uint(l3), __float_as_uint(l2));
            u16t* wp = &smem[(m * 16 + l15) * K2P + khb];
            *(uint2*)wp = hw;
            *(uint2*)(wp + HPL) = lw;
        }
    }
    __syncthreads();

    // ---- GEMM2 (swapped): D[slot][channel] = Hp * W2, weights streamed per kt
    int eaddr[MT2];
#pragma unroll
    for (int m = 0; m < MT2; m++) {
        const int nd_s = (m / 3) * 8 + 2 * (l15 >> 2) + ((l15 >> 1) & 1);
        const int i_s = (m % 3) * 2 + (l15 & 1);
        eaddr[m] = (nd_s * KNN + i_s) * K2P + quad * 8;
    }

    f32x4 acc2[NW][MT2];
#pragma unroll
    for (int t = 0; t < NW; t++)
#pragma unroll
        for (int m = 0; m < MT2; m++) acc2[t][m] = (f32x4){0.f, 0.f, 0.f, 0.f};

#pragma unroll
    for (int kt = 0; kt < K2T; kt++) {
        const int cur = kt & 1, nxt = cur ^ 1;
        if (kt + 1 < K2T) {
#pragma unroll
            for (int t = 0; t < NW; t++) {
                const int fi = ((wv * NW + t) * K2T + kt + 1) * 64 + lane;
                wbh[nxt][t].u = wfb_hi[fi];
                wbl[nxt][t].u = wfb_lo[fi];
            }
        }
#pragma unroll
        for (int m = 0; m < MT2; m++) {
            const u16t* p = &smem[eaddr[m] + kt * 32];
            U16 dh, dl;
            dh.u = *(const uint4*)p;
            dl.u = *(const uint4*)(p + HPL);
#pragma unroll
            for (int t = 0; t < NW; t++) {
                acc2[t][m] = mfma16(dh.b, wbh[cur][t].b, acc2[t][m]);
                acc2[t][m] = mfma16(dh.b, wbl[cur][t].b, acc2[t][m]);
                acc2[t][m] = mfma16(dl.b, wbh[cur][t].b, acc2[t][m]);
            }
        }
    }

    // ---- segment max: fully in-lane (slot perm), 2 nodes per lane per m-triple
#pragma unroll
    for (int t = 0; t < NW; t++) {
        const int nb = (wv * NW + t) * 16;
        const float bias = bb[nb + l15];
#pragma unroll
        for (int g = 0; g < MT2 / 3; g++) {
#pragma unroll
            for (int rp = 0; rp < 2; rp++) {
                float v = fmaxf(
                    fmaxf(fmaxf(acc2[t][3 * g + 0][2 * rp], acc2[t][3 * g + 0][2 * rp + 1]),
                          fmaxf(acc2[t][3 * g + 1][2 * rp], acc2[t][3 * g + 1][2 * rp + 1])),
                    fmaxf(acc2[t][3 * g + 2][2 * rp], acc2[t][3 * g + 2][2 * rp + 1]));
                v = fmaxf(v + bias, 0.f);
                const int node = node0 + g * 8 + 2 * quad + rp;
                const size_t oidx = (size_t)node * H + nb + l15;
                if constexpr (OUTP) {
                    split_store(&oh[oidx], &ol[oidx], v);
                } else {
                    outf[oidx] = v;
                }
            }
        }
    }
}

// ---------------------------------------------------------------------------
extern "C" void kernel_launch(void* const* d_in, const int* in_sizes, int n_in,
                              void* d_out, int out_size, void* d_ws, size_t ws_size,
                              hipStream_t stream) {
    const float* pos = (const float*)d_in[0];
    const int* ei = (const int*)d_in[1];
    const float* W1a = (const float*)d_in[2];
    const float* b1a = (const float*)d_in[3];
    const float* W1b = (const float*)d_in[4];
    const float* b1b = (const float*)d_in[5];
    const float* W2a = (const float*)d_in[6];
    const float* b2a = (const float*)d_in[7];
    const float* W2b = (const float*)d_in[8];
    const float* b2b = (const float*)d_in[9];
    const float* W3a = (const float*)d_in[10];
    const float* b3a = (const float*)d_in[11];
    const float* W3b = (const float*)d_in[12];
    const float* b3b = (const float*)d_in[13];

    u16t* h1h = (u16t*)d_ws;                       // [NODES][32] hi plane
    u16t* h1l = h1h + (size_t)NODES * 32;          // [NODES][32] lo plane
    u16t* h2h = h1l + (size_t)NODES * 32;          // [NODES][64] hi plane
    u16t* h2l = h2h + (size_t)NODES * 64;          // [NODES][64] lo plane
    uint4* wf = (uint4*)(h2l + (size_t)NODES * 64);
    // fragment uint4 offsets:
    //   W1a h/l @0/128, W1b @256/384, W2a (x-rows) @512/768, W2b @1024/1536,
    //   W3a (full 67 rows) @2048/3584, W3b @5120/7168; end 9216

    prep_all<<<19, 256, 0, stream>>>(W1a, W1b, W2a, W2b, W3a, W3b, wf);

    // Layer 1: CX=3 (pos-only), H=32, 2 waves, NB=8 (LDS ~8KB -> 16 blocks/CU,
    // 32 waves = full occupancy for the gather-latency-bound layer), pos in K
    pnconv_mfma<3, 32, 2, 8, true, false><<<NODES / 8, 128, 0, stream>>>(
        nullptr, nullptr, pos, ei,
        wf + 0, wf + 128, b1a, wf + 256, wf + 384, b1b,
        nullptr, nullptr, h1h, h1l);

    // Layer 2: CX=32, H=64, 4 waves (NW=1), NB=8 — fp32 Δpos path (K1T=1);
    // LDS 27.6->14KB -> 8 blocks/CU = 32 waves (was 5 blocks/20 waves)
    pnconv_mfma<32, 64, 4, 8, true, true><<<NODES / 8, 256, 0, stream>>>(
        h1h, h1l, pos, ei,
        wf + 512, wf + 768, b2a, wf + 1024, wf + 1536, b2b,
        W2a, nullptr, h2h, h2l);

    // Layer 3: CX=64, H=128, 4 waves (NW=2), NB=8, fp32 output — pos in K (K1T=3)
    // (unchanged: best-measured config, 89.4us)
    pnconv_mfma<64, 128, 4, 8, false, false><<<NODES / 8, 256, 0, stream>>>(
        h2h, h2l, pos, ei,
        wf + 2048, wf + 3584, b3a, wf + 5120, wf + 7168, b3b,
        nullptr, (float*)d_out, nullptr, nullptr);
}

// Round 7
// 224.461 us; speedup vs baseline: 1.3749x; 1.0030x over previous
//
#include <hip/hip_runtime.h>

#define NODES 100000
#define KNN 6

typedef unsigned short u16t;
typedef __attribute__((ext_vector_type(8))) short bf16x8;
typedef __attribute__((ext_vector_type(4))) float f32x4;
union U16 { uint4 u; bf16x8 b; };

__device__ inline f32x4 mfma16(bf16x8 a, bf16x8 b, f32x4 c) {
    return __builtin_amdgcn_mfma_f32_16x16x32_bf16(a, b, c, 0, 0, 0);
}
// pack top-16 bits of two fp32 words (u0 -> low half, u1 -> high half)
__device__ inline unsigned top2(unsigned u1, unsigned u0) {
    return __builtin_amdgcn_perm(u1, u0, 0x07060302u);
}
__device__ inline u16t bf16_rn(float x) {
    unsigned u = __float_as_uint(x);
    return (u16t)((u + 0x7FFF + ((u >> 16) & 1)) >> 16);
}
__device__ inline float bf16_f(u16t h) {
    return __uint_as_float(((unsigned)h) << 16);
}
// truncation split into hi/lo bf16 planes
__device__ inline void split_store(u16t* hp, u16t* lp, float v) {
    const unsigned u = __float_as_uint(v);
    *hp = (u16t)(u >> 16);
    const float hif = __uint_as_float(u & 0xFFFF0000u);
    *lp = (u16t)(__float_as_uint(v - hif) >> 16);
}

// ---------------------------------------------------------------------------
// Weight prep: W[CIN_][N_] fp32 -> MFMA A-operand fragments (hi/lo bf16).
// Fragment (tile t, k-tile kt): elem[n = t*16 + (lane&15)][k = kt*32 + (lane>>4)*8 + j]
template <int CIN_, int N_>
__device__ void prep_dev(const float* __restrict__ W,
                         uint4* __restrict__ fh, uint4* __restrict__ fl, int idx) {
    constexpr int KT = (CIN_ + 31) / 32;
    constexpr int NTt = N_ / 16;
    if (idx >= NTt * KT * 64) return;
    const int lane = idx & 63;
    const int fk = idx >> 6;
    const int kt = fk % KT, t = fk / KT;
    const int n = t * 16 + (lane & 15);
    const int kbase = kt * 32 + (lane >> 4) * 8;
    unsigned h[4], l[4];
    for (int p = 0; p < 4; p++) {
        u16t hh[2], ll[2];
        for (int q = 0; q < 2; q++) {
            const int c = kbase + 2 * p + q;
            const float w = (c < CIN_) ? W[(size_t)c * N_ + n] : 0.f;
            const u16t hi = bf16_rn(w);
            hh[q] = hi;
            ll[q] = bf16_rn(w - bf16_f(hi));
        }
        h[p] = (unsigned)hh[0] | ((unsigned)hh[1] << 16);
        l[p] = (unsigned)ll[0] | ((unsigned)ll[1] << 16);
    }
    fh[idx] = make_uint4(h[0], h[1], h[2], h[3]);
    fl[idx] = make_uint4(l[0], l[1], l[2], l[3]);
}

// W2a: x-rows only (L2 uses the fp32 Δpos VALU path).
// W3a: full 67 rows (L3 keeps pos in the K dimension — the VALU path regressed
//      there: removed MFMA fraction too small vs added serial VALU chain).
__global__ void prep_all(const float* W1a, const float* W1b,
                         const float* W2a, const float* W2b,
                         const float* W3a, const float* W3b, uint4* wf) {
    const int b = blockIdx.x, t = threadIdx.x;
    if (b == 0)      prep_dev<6, 32>(W1a, wf + 0, wf + 128, t);
    else if (b == 1) prep_dev<32, 32>(W1b, wf + 256, wf + 384, t);
    else if (b == 2) prep_dev<32, 64>(W2a, wf + 512, wf + 768, t);
    else if (b < 5)  prep_dev<64, 64>(W2b, wf + 1024, wf + 1536, (b - 3) * 256 + t);
    else if (b < 11) prep_dev<67, 128>(W3a, wf + 2048, wf + 3584, (b - 5) * 256 + t);
    else             prep_dev<128, 128>(W3b, wf + 5120, wf + 7168, (b - 11) * 256 + t);
}

// ---------------------------------------------------------------------------
// MFMA PointNetConv layer (all 3 layers). Features stored INTERLEAVED per node:
// record [hi CX ch | lo CX ch] (2*CX u16, 128B-aligned for CX=32). One random
// cache-line touch per edge gather instead of two separate-plane touches —
// L1/L2 are gather-latency-bound on request count (R6: occupancy alone gave
// only -8us of the predicted -20).
// DPOS=false: pos/Δpos channels inside the GEMM1 K dimension (CIN = CX+3, padded).
// DPOS=true : GEMM1 K = x only (exact K-tiles); the Δpos·Wa_p term is added in
//             exact fp32 VALU from an LDS-staged Δpos[E][4] array. Only pays when
//             the removed K-tile is a large fraction of GEMM1 (L2: 50%; L3: no).
// GEMM1: A = weights (regs, kt-streamed), B = data (LDS)   rows=channels, cols=edges
// GEMM2: A = data (LDS), B = weights (regs, kt-streamed)   rows=slots,    cols=channels
//
// Session ledger (dispatch-level, in-run evidence):
//   L3 pos-in-K ~89-95us beats L3 DPOS 105.8us; L2 DPOS beats L2 pos-in-K ~-21us.
//   NWAVE=2 (R3): halves LDS traffic+conflicts but cuts resident waves -> regressed.
//   KSPLIT @ min-waves 6 (R4): VGPR cap below live set -> scratch spill, +377MB HBM.
//   NB 16->8 on L1/L2 (R6): 32 waves/CU, total -7us (modest; latency remains).
//
// GEMM2 slot permutation (no padding; E = 48*g tiles of 16):
//   slot s (tile m, w = s&15, quad q = w>>2, reg r = w&3) maps to
//   edge = node*6 + i,  node = (m/3)*8 + 2q + (r>>1),  i = (m%3)*2 + (r&1).
// With this map a node's 6 edges live in ONE lane across the m-triple's
// reg-pairs -> segment max is 6 in-lane fmax, no shuffles, no predication.
template <int CX, int H, int NWAVE, int NB, bool OUTP, bool DPOS>
__global__ __launch_bounds__(NWAVE * 64, 4) void pnconv_mfma(
    const u16t* __restrict__ x,      // interleaved [node][2*CX]; null for L1
    const float* __restrict__ pos, const int* __restrict__ ei,
    const uint4* __restrict__ wfa_hi, const uint4* __restrict__ wfa_lo,
    const float* __restrict__ ba,
    const uint4* __restrict__ wfb_hi, const uint4* __restrict__ wfb_lo,
    const float* __restrict__ bb,
    const float* __restrict__ wpos,  // raw Wa (fp32 [CIN][H]) pos rows; DPOS only
    float* __restrict__ outf,        // fp32 out (OUTP=false)
    u16t* __restrict__ o)            // interleaved [node][2*H] out (OUTP=true)
{
    constexpr int NTH = NWAVE * 64;
    constexpr int CIN = DPOS ? CX : CX + 3;  // GEMM1 K channels
    constexpr int K1T = (CIN + 31) / 32;
    constexpr int K2T = H / 32;
    constexpr int NW = (H / 16) / NWAVE;     // channel tiles per wave
    constexpr int E = NB * KNN;
    constexpr int MT1 = E / 16;              // edge tiles (GEMM1 N)
    constexpr int MT2 = E / 16;              // slot tiles (GEMM2 M), unpadded
    constexpr int K1P = K1T * 32 + 8;        // ushort row strides (16B aligned)
    constexpr int K2P = K2T * 32 + 8;
    constexpr int APL = E * K1P;
    constexpr int HPL = E * K2P;
    constexpr int SM = (2 * APL > 2 * HPL) ? 2 * APL : 2 * HPL;
    static_assert(E % 48 == 0 && E <= NTH, "tile shape");
    static_assert(MT2 % 3 == 0, "slot perm needs m-triples");
    static_assert(!DPOS || (2 * APL + E * 8) <= SM, "dpos overlay fits");

    __shared__ __align__(16) u16t smem[SM];
    __shared__ int srcs[E];
    float* const dpf = (float*)&smem[2 * APL];   // DPOS: fp32 Δpos rows [E][4]

    const int tid = threadIdx.x;
    const int lane = tid & 63, wv = tid >> 6;
    const int l15 = lane & 15, quad = lane >> 4;
    const int node0 = blockIdx.x * NB;
    const long e0 = (long)node0 * KNN;

    if (tid < E) srcs[tid] = ei[e0 + tid];

    // GEMM1 weights: kt=0 preload (ping-pong streamed in the loop)
    U16 wah[2][NW], wal[2][NW];
#pragma unroll
    for (int t = 0; t < NW; t++) {
        const int fi = ((wv * NW + t) * K1T) * 64 + lane;
        wah[0][t].u = wfa_hi[fi];
        wal[0][t].u = wfa_lo[fi];
    }
    // pos-row weights Wa[CX+d][ch..ch+3] for the fp32 Δpos term
    f32x4 wpp[NW][3];
    if constexpr (DPOS) {
#pragma unroll
        for (int t = 0; t < NW; t++)
#pragma unroll
            for (int d = 0; d < 3; d++)
                wpp[t][d] = *(const f32x4*)&wpos[(size_t)(CX + d) * H +
                                                (wv * NW + t) * 16 + quad * 4];
    }
    __syncthreads();

    // ---- stage feature planes into LDS (chunk-rotated: bank-conflict-free)
    // Interleaved source: one ~2*CX*2-byte record per src node -> one cache
    // line per edge at CX=32 (was two with separate hi/lo planes).
    if constexpr (CX % 8 == 0) {
        constexpr int C8 = CX / 8;
        for (int i = tid; i < E * C8; i += NTH) {
            const int e = i / C8, c0 = i % C8;
            const int c = (c0 + e) & (C8 - 1);   // rotate lane->chunk within the row
            const size_t sb = (size_t)srcs[e] * (2 * CX) + c * 8;
            *(uint4*)&smem[e * K1P + c * 8] = *(const uint4*)&x[sb];
            *(uint4*)&smem[APL + e * K1P + c * 8] = *(const uint4*)&x[sb + CX];
        }
    }
    for (int i = tid; i < E * 3; i += NTH) {
        const int e = i / 3, d = i - 3 * (i / 3);
        const int s = srcs[e], nd = node0 + e / KNN;
        const float sp = pos[3 * s + d];
        const float dl = sp - pos[3 * nd + d];
        if constexpr (DPOS) {
            dpf[e * 4 + d] = dl;                 // exact fp32, used post-GEMM1
        } else {
            if constexpr (CX == 3)
                split_store(&smem[e * K1P + d], &smem[APL + e * K1P + d], sp);
            split_store(&smem[e * K1P + CX + d], &smem[APL + e * K1P + CX + d], dl);
        }
    }
    if constexpr (!DPOS) {
        // zero the K padding (garbage bf16 could be NaN; NaN*0 = NaN)
        constexpr int PADA = (CIN + 7) & ~7;
        constexpr int NU4 = (K1P - PADA) / 8;
        for (int i = tid; i < 2 * E; i += NTH) {
            const int pl = (i >= E) ? 1 : 0;
            const int e = i - pl * E;
            u16t* row = &smem[pl * APL + e * K1P];
            for (int k = CIN; k < PADA; k++) row[k] = 0;
            for (int j = 0; j < NU4; j++) *(uint4*)&row[PADA + j * 8] = make_uint4(0, 0, 0, 0);
        }
    }
    __syncthreads();

    // ---- GEMM1: D[channel][edge] = W1^T * A^T (3-term bf16 split)
    f32x4 acc1[NW][MT1];
#pragma unroll
    for (int t = 0; t < NW; t++)
#pragma unroll
        for (int m = 0; m < MT1; m++) acc1[t][m] = (f32x4){0.f, 0.f, 0.f, 0.f};

#pragma unroll
    for (int kt = 0; kt < K1T; kt++) {
        const int cur = kt & 1, nxt = cur ^ 1;
        if (kt + 1 < K1T) {
#pragma unroll
            for (int t = 0; t < NW; t++) {      // prefetch next kt's weights
                const int fi = ((wv * NW + t) * K1T + kt + 1) * 64 + lane;
                wah[nxt][t].u = wfa_hi[fi];
                wal[nxt][t].u = wfa_lo[fi];
            }
        }
#pragma unroll
        for (int m = 0; m < MT1; m++) {
            const u16t* p = &smem[(m * 16 + l15) * K1P + kt * 32 + quad * 8];
            U16 dh, dl;
            dh.u = *(const uint4*)p;
            dl.u = *(const uint4*)(p + APL);
#pragma unroll
            for (int t = 0; t < NW; t++) {
                acc1[t][m] = mfma16(wah[cur][t].b, dh.b, acc1[t][m]);
                acc1[t][m] = mfma16(wah[cur][t].b, dl.b, acc1[t][m]);
                acc1[t][m] = mfma16(wal[cur][t].b, dh.b, acc1[t][m]);
            }
        }
    }

    // GEMM2 weights: kt=0 preload (latency covered by epilogue + barrier)
    U16 wbh[2][NW], wbl[2][NW];
#pragma unroll
    for (int t = 0; t < NW; t++) {
        const int fi = ((wv * NW + t) * K2T) * 64 + lane;
        wbh[0][t].u = wfb_hi[fi];
        wbl[0][t].u = wfb_lo[fi];
    }

    // ---- Δpos·Wa_p term, exact fp32 (DPOS layers only)
    if constexpr (DPOS) {
#pragma unroll
        for (int m = 0; m < MT1; m++) {
            const f32x4 dp = *(const f32x4*)&dpf[(m * 16 + l15) * 4];
#pragma unroll
            for (int t = 0; t < NW; t++)
#pragma unroll
                for (int j = 0; j < 4; j++)
                    acc1[t][m][j] += wpp[t][0][j] * dp[0] + wpp[t][1][j] * dp[1]
                                   + wpp[t][2][j] * dp[2];
        }
    }
    __syncthreads();   // all A/dpos reads done; smem becomes Hp planes

    // ---- bias + relu + trunc-split, write Hp planes
#pragma unroll
    for (int t = 0; t < NW; t++) {
        const int khb = (wv * NW + t) * 16 + quad * 4;
        const float4 bs = *(const float4*)&ba[khb];
#pragma unroll
        for (int m = 0; m < MT1; m++) {
            const float v0 = fmaxf(acc1[t][m][0] + bs.x, 0.f);
            const float v1 = fmaxf(acc1[t][m][1] + bs.y, 0.f);
            const float v2 = fmaxf(acc1[t][m][2] + bs.z, 0.f);
            const float v3 = fmaxf(acc1[t][m][3] + bs.w, 0.f);
            const unsigned u0 = __float_as_uint(v0), u1 = __float_as_uint(v1);
            const unsigned u2 = __float_as_uint(v2), u3 = __float_as_uint(v3);
            uint2 hw, lw;
            hw.x = top2(u1, u0);
            hw.y = top2(u3, u2);
            const float l0 = v0 - __uint_as_float(u0 & 0xFFFF0000u);
            const float l1 = v1 - __uint_as_float(u1 & 0xFFFF0000u);
            const float l2 = v2 - __uint_as_float(u2 & 0xFFFF0000u);
            const float l3 = v3 - __uint_as_float(u3 & 0xFFFF0000u);
            lw.x = top2(__float_as_uint(l1), __float_as_uint(l0));
            lw.y = top2(__float_as_uint(l3), __float_as_uint(l2));
            u16t* wp = &smem[(m * 16 + l15) * K2P + khb];
            *(uint2*)wp = hw;
            *(uint2*)(wp + HPL) = lw;
        }
    }
    __syncthreads();

    // ---- GEMM2 (swapped): D[slot][channel] = Hp * W2, weights streamed per kt
    int eaddr[MT2];
#pragma unroll
    for (int m = 0; m < MT2; m++) {
        const int nd_s = (m / 3) * 8 + 2 * (l15 >> 2) + ((l15 >> 1) & 1);
        const int i_s = (m % 3) * 2 + (l15 & 1);
        eaddr[m] = (nd_s * KNN + i_s) * K2P + quad * 8;
    }

    f32x4 acc2[NW][MT2];
#pragma unroll
    for (int t = 0; t < NW; t++)
#pragma unroll
        for (int m = 0; m < MT2; m++) acc2[t][m] = (f32x4){0.f, 0.f, 0.f, 0.f};

#pragma unroll
    for (int kt = 0; kt < K2T; kt++) {
        const int cur = kt & 1, nxt = cur ^ 1;
        if (kt + 1 < K2T) {
#pragma unroll
            for (int t = 0; t < NW; t++) {
                const int fi = ((wv * NW + t) * K2T + kt + 1) * 64 + lane;
                wbh[nxt][t].u = wfb_hi[fi];
                wbl[nxt][t].u = wfb_lo[fi];
            }
        }
#pragma unroll
        for (int m = 0; m < MT2; m++) {
            const u16t* p = &smem[eaddr[m] + kt * 32];
            U16 dh, dl;
            dh.u = *(const uint4*)p;
            dl.u = *(const uint4*)(p + HPL);
#pragma unroll
            for (int t = 0; t < NW; t++) {
                acc2[t][m] = mfma16(dh.b, wbh[cur][t].b, acc2[t][m]);
                acc2[t][m] = mfma16(dh.b, wbl[cur][t].b, acc2[t][m]);
                acc2[t][m] = mfma16(dl.b, wbh[cur][t].b, acc2[t][m]);
            }
        }
    }

    // ---- segment max: fully in-lane (slot perm), 2 nodes per lane per m-triple
#pragma unroll
    for (int t = 0; t < NW; t++) {
        const int nb = (wv * NW + t) * 16;
        const float bias = bb[nb + l15];
#pragma unroll
        for (int g = 0; g < MT2 / 3; g++) {
#pragma unroll
            for (int rp = 0; rp < 2; rp++) {
                float v = fmaxf(
                    fmaxf(fmaxf(acc2[t][3 * g + 0][2 * rp], acc2[t][3 * g + 0][2 * rp + 1]),
                          fmaxf(acc2[t][3 * g + 1][2 * rp], acc2[t][3 * g + 1][2 * rp + 1])),
                    fmaxf(acc2[t][3 * g + 2][2 * rp], acc2[t][3 * g + 2][2 * rp + 1]));
                v = fmaxf(v + bias, 0.f);
                const int node = node0 + g * 8 + 2 * quad + rp;
                if constexpr (OUTP) {
                    u16t* op = &o[(size_t)node * (2 * H) + nb + l15];
                    split_store(op, op + H, v);   // hi|lo halves of one record
                } else {
                    outf[(size_t)node * H + nb + l15] = v;
                }
            }
        }
    }
}

// ---------------------------------------------------------------------------
extern "C" void kernel_launch(void* const* d_in, const int* in_sizes, int n_in,
                              void* d_out, int out_size, void* d_ws, size_t ws_size,
                              hipStream_t stream) {
    const float* pos = (const float*)d_in[0];
    const int* ei = (const int*)d_in[1];
    const float* W1a = (const float*)d_in[2];
    const float* b1a = (const float*)d_in[3];
    const float* W1b = (const float*)d_in[4];
    const float* b1b = (const float*)d_in[5];
    const float* W2a = (const float*)d_in[6];
    const float* b2a = (const float*)d_in[7];
    const float* W2b = (const float*)d_in[8];
    const float* b2b = (const float*)d_in[9];
    const float* W3a = (const float*)d_in[10];
    const float* b3a = (const float*)d_in[11];
    const float* W3b = (const float*)d_in[12];
    const float* b3b = (const float*)d_in[13];

    u16t* h1 = (u16t*)d_ws;                        // [NODES][64]  hi|lo interleaved
    u16t* h2 = h1 + (size_t)NODES * 64;            // [NODES][128] hi|lo interleaved
    uint4* wf = (uint4*)(h2 + (size_t)NODES * 128);
    // fragment uint4 offsets:
    //   W1a h/l @0/128, W1b @256/384, W2a (x-rows) @512/768, W2b @1024/1536,
    //   W3a (full 67 rows) @2048/3584, W3b @5120/7168; end 9216

    prep_all<<<19, 256, 0, stream>>>(W1a, W1b, W2a, W2b, W3a, W3b, wf);

    // Layer 1: CX=3 (pos-only), H=32, 2 waves, NB=8, pos in K
    pnconv_mfma<3, 32, 2, 8, true, false><<<NODES / 8, 128, 0, stream>>>(
        nullptr, pos, ei,
        wf + 0, wf + 128, b1a, wf + 256, wf + 384, b1b,
        nullptr, nullptr, h1);

    // Layer 2: CX=32, H=64, 4 waves (NW=1), NB=8 — fp32 Δpos path (K1T=1);
    // gather now one 128B record/edge (was two 64B plane touches)
    pnconv_mfma<32, 64, 4, 8, true, true><<<NODES / 8, 256, 0, stream>>>(
        h1, pos, ei,
        wf + 512, wf + 768, b2a, wf + 1024, wf + 1536, b2b,
        W2a, nullptr, h2);

    // Layer 3: CX=64, H=128, 4 waves (NW=2), NB=8, fp32 output — pos in K (K1T=3)
    pnconv_mfma<64, 128, 4, 8, false, false><<<NODES / 8, 256, 0, stream>>>(
        h2, pos, ei,
        wf + 2048, wf + 3584, b3a, wf + 5120, wf + 7168, b3b,
        nullptr, (float*)d_out, nullptr);
}